// Round 13
// baseline (328.780 us; speedup 1.0000x reference)
//
#include <hip/hip_runtime.h>
#include <math.h>

// ---------------------------------------------------------------------------
// B=64 graphs, NN=133 nodes. 8 plain launches:
//  K1 prep_emb : blk<399 emb GEMM | 399..2526 fwd ballot prep (wave/row) |
//                2527..4654 rev ballot prep (wave/column, out-neighbors)
//  K2 gemm1 t1=h0@gc1_w (532 tiles) + zero p1 (grid-stride blocks)
//  K3 spmmpool1: y1[j,.] in regs -> scatter atomicMax to p1[r,.] (rev list)
//  K4 gemm2 t2=p1@gc2_w (266) + zero p2
//  K5 spmmpool2 -> p2
//  K6 gemm3 t3=p2@gc3_w (266) + zero p3
//  K7 spmmpool3 -> p3
//  K8 tail: t4[i]=p3[i,:].gc4_w (coalesced, no gathers) + y4 + fc1 + fin
// Key invariant: y>=0 (post-relu), p zero-init -> atomicMax on uint bit
// pattern == float max; rows with no in-edges stay 0 (matches has_nb mask).
// Fwd lists: front=a>1e-5 (spmm+pool), back=0<a<=1e-5 (spmm only).
// ---------------------------------------------------------------------------

#define NN 133
#define NPAIR 64

// ---------------- GEMM core: one 64x64 tile, prefetch-pipelined -------------
template<int VECA, int VECB, int RELU, int BIAS>
__device__ __forceinline__ void gemm_tile_core(
    const float* __restrict__ A, int lda, int K,
    const float* __restrict__ W, int N,
    const float* __restrict__ bias,
    float* __restrict__ C, int ldc, int padN,
    int m0, int n0, float (*As)[68], float (*Bs)[68], int tid)
{
    const int la_m = tid >> 2, la_k = (tid & 3) * 4;   // A: 64 rows x 4 float4
    const int lb_k = tid >> 4, lb_n = (tid & 15) * 4;  // B: 16 k-rows x 16 f4
    const int tx = tid & 15, ty = tid >> 4;
    const int r = m0 + la_m;

    float pa[4], pb[4];
    if (VECA) {
        float4 v = *reinterpret_cast<const float4*>(A + (size_t)r * lda + la_k);
        pa[0] = v.x; pa[1] = v.y; pa[2] = v.z; pa[3] = v.w;
    } else {
#pragma unroll
        for (int j = 0; j < 4; ++j) {
            int gk = la_k + j;
            pa[j] = (gk < K) ? A[(size_t)r * lda + gk] : 0.f;
        }
    }
    if (VECB) {
        if (lb_k < K) {
            float4 v = *reinterpret_cast<const float4*>(
                W + (size_t)lb_k * N + n0 + lb_n);
            pb[0] = v.x; pb[1] = v.y; pb[2] = v.z; pb[3] = v.w;
        } else { pb[0] = pb[1] = pb[2] = pb[3] = 0.f; }
    } else {
#pragma unroll
        for (int j = 0; j < 4; ++j) {
            int gn = n0 + lb_n + j;
            pb[j] = (lb_k < K && gn < N) ? W[(size_t)lb_k * N + gn] : 0.f;
        }
    }

    float acc[4][4] = {};
    for (int k0 = 0; k0 < K; k0 += 16) {
        __syncthreads();
#pragma unroll
        for (int j = 0; j < 4; ++j) As[la_k + j][la_m] = pa[j];
        *reinterpret_cast<float4*>(&Bs[lb_k][lb_n]) =
            make_float4(pb[0], pb[1], pb[2], pb[3]);
        __syncthreads();
        const int kn = k0 + 16;
        if (kn < K) {   // prefetch next k-tile (overlaps FMA block)
            if (VECA) {
                float4 v = *reinterpret_cast<const float4*>(
                    A + (size_t)r * lda + kn + la_k);
                pa[0] = v.x; pa[1] = v.y; pa[2] = v.z; pa[3] = v.w;
            } else {
#pragma unroll
                for (int j = 0; j < 4; ++j) {
                    int gk = kn + la_k + j;
                    pa[j] = (gk < K) ? A[(size_t)r * lda + gk] : 0.f;
                }
            }
            int gk = kn + lb_k;
            if (VECB) {
                if (gk < K) {
                    float4 v = *reinterpret_cast<const float4*>(
                        W + (size_t)gk * N + n0 + lb_n);
                    pb[0] = v.x; pb[1] = v.y; pb[2] = v.z; pb[3] = v.w;
                } else { pb[0] = pb[1] = pb[2] = pb[3] = 0.f; }
            } else {
#pragma unroll
                for (int j = 0; j < 4; ++j) {
                    int gn = n0 + lb_n + j;
                    pb[j] = (gk < K && gn < N) ? W[(size_t)gk * N + gn] : 0.f;
                }
            }
        }
#pragma unroll
        for (int k = 0; k < 16; ++k) {
            float4 av = *reinterpret_cast<const float4*>(&As[k][ty * 4]);
            float4 bv = *reinterpret_cast<const float4*>(&Bs[k][tx * 4]);
            float a[4] = {av.x, av.y, av.z, av.w};
            float b[4] = {bv.x, bv.y, bv.z, bv.w};
#pragma unroll
            for (int i = 0; i < 4; ++i)
#pragma unroll
                for (int j = 0; j < 4; ++j)
                    acc[i][j] = fmaf(a[i], b[j], acc[i][j]);
        }
    }
#pragma unroll
    for (int i = 0; i < 4; ++i) {
        int gm = m0 + ty * 4 + i;
#pragma unroll
        for (int j = 0; j < 4; ++j) {
            int gn = n0 + tx * 4 + j;
            if (gn < padN) {
                float v = 0.f;
                if (gn < N) {
                    v = acc[i][j];
                    if (BIAS) v += bias[gn];
                    if (RELU) v = fmaxf(v, 0.f);
                }
                C[(size_t)gm * ldc + gn] = v;
            }
        }
    }
}

// GEMM tiles + (extra blocks) grid-stride zero of next p-buffer.
template<int VECA, int VECB>
__global__ __launch_bounds__(256)
void gemm_zero_k(const float* __restrict__ A, int lda, int K,
                 const float* __restrict__ W, int N,
                 float* __restrict__ C, int ldc, int padN, int tiles_n,
                 int ntiles, float4* __restrict__ zp, int zn4)
{
    __shared__ float As[16][68];
    __shared__ float Bs[16][68];
    const int t = blockIdx.x;
    if (t < ntiles) {
        gemm_tile_core<VECA, VECB, 0, 0>(
            A, lda, K, W, N, nullptr, C, ldc, padN,
            (t / tiles_n) * 64, (t % tiles_n) * 64, As, Bs, threadIdx.x);
    } else {
        const int nzb = gridDim.x - ntiles;
        const float4 z = make_float4(0.f, 0.f, 0.f, 0.f);
        for (int i = (t - ntiles) * 256 + threadIdx.x; i < zn4; i += nzb * 256)
            zp[i] = z;
    }
}

// -------- K1: emb GEMM | fwd ballot prep (wave/row) | rev prep (wave/col) ---
__global__ __launch_bounds__(256)
void prep_emb_k(const float* __restrict__ x,
                const float* __restrict__ emb_w, const float* __restrict__ emb_b,
                const float* __restrict__ adj,
                float2* __restrict__ pairs, int2* __restrict__ cnts,
                int* __restrict__ revi, int* __restrict__ revc,
                float* __restrict__ h0)
{
    __shared__ float As[16][68];
    __shared__ float Bs[16][68];
    const int tid = threadIdx.x;
    const int wave = tid >> 6, lane = tid & 63;
    const unsigned long long lt = (1ull << lane) - 1ull;
    if (blockIdx.x < 399) {
        const int t = blockIdx.x;
        gemm_tile_core<0, 0, 1, 1>(
            x, 75, 75, emb_w, 150, emb_b, h0, 152, 152,
            (t / 3) * 64, (t % 3) * 64, As, Bs, tid);
    } else if (blockIdx.x < 399 + 2128) {
        // fwd lists: one wave per adjacency row r
        const int r = (blockIdx.x - 399) * 4 + wave;   // 0..8511
        const float* ar = adj + (size_t)r * NN;
        float2* pb = pairs + (size_t)r * NPAIR;
        int base0 = 0, base1 = 0;
#pragma unroll
        for (int s = 0; s < 3; ++s) {
            const int j = lane + 64 * s;
            const float a = (j < NN) ? ar[j] : 0.f;
            const bool f = a > 1e-5f;
            const bool g = (a > 0.f) && !f;
            const unsigned long long mf = __ballot(f);
            const unsigned long long mg = __ballot(g);
            if (f) pb[base0 + __popcll(mf & lt)] =
                       make_float2(a, __int_as_float(j));
            if (g) pb[(NPAIR - 1) - (base1 + __popcll(mg & lt))] =
                       make_float2(a, __int_as_float(j));
            base0 += __popcll(mf);
            base1 += __popcll(mg);
        }
        if (lane == 0) cnts[r] = make_int2(base0, base1);
    } else {
        // rev lists: one wave per (graph b, column j) = out-neighbors of j
        const int gcol = (blockIdx.x - 399 - 2128) * 4 + wave;  // 0..8511
        const int b = gcol / NN, j = gcol - b * NN;
        const float* ab = adj + (size_t)b * NN * NN + j;
        int* rv = revi + (size_t)gcol * NPAIR;
        int base = 0;
#pragma unroll
        for (int s = 0; s < 3; ++s) {
            const int r = lane + 64 * s;
            const float a = (r < NN) ? ab[(size_t)r * NN] : 0.f;
            const bool f = a > 1e-5f;
            const unsigned long long mf = __ballot(f);
            if (f) rv[base + __popcll(mf & lt)] = r;
            base += __popcll(mf);
        }
        if (lane == 0) revc[gcol] = base;
    }
}

// -------- spmm+pool scatter: y[j,.] in regs -> atomicMax p[r,.] -------------
template<int GRP>
__global__ __launch_bounds__(256)
void spmmpool_k(const float* __restrict__ t, int ld, int N,
                const float* __restrict__ bias,
                const float2* __restrict__ pairs, const int2* __restrict__ cnts,
                const int* __restrict__ revi, const int* __restrict__ revc,
                unsigned* __restrict__ p)   // zero-initialized, ld floats/row
{
    const int wave = threadIdx.x >> 6, lane = threadIdx.x & 63;
    const int gj = blockIdx.x * 4 + wave;       // 0..8511 (graph b, node j)
    const int b = gj / NN;
    const int bbase = b * NN;
    int  c[GRP], sc[GRP];
    float bi[GRP];
#pragma unroll
    for (int u = 0; u < GRP; ++u) {
        c[u] = u * 64 + lane;
        sc[u] = min(c[u], N - 1);               // clamp for safe loads
        bi[u] = (c[u] < N) ? bias[c[u]] : 0.f;
    }
    const float2* pb = pairs + (size_t)gj * NPAIR;
    const float4* pq = reinterpret_cast<const float4*>(pb);
    const int2 cc = cnts[gj];
    const float* tb = t + (size_t)bbase * ld;

    // y[j, c(u)] = relu(bias + sum_k a_jk t[k, c(u)]) via 4 gather chains
    float a0[GRP], a1[GRP], a2[GRP], a3[GRP];
#pragma unroll
    for (int u = 0; u < GRP; ++u) { a0[u] = a1[u] = a2[u] = a3[u] = 0.f; }
    int q = 0;
    for (; q + 4 <= cc.x; q += 4) {
        float4 pA = pq[q >> 1], pB = pq[(q >> 1) + 1];
        const float* r0 = tb + (size_t)__float_as_int(pA.y) * ld;
        const float* r1 = tb + (size_t)__float_as_int(pA.w) * ld;
        const float* r2 = tb + (size_t)__float_as_int(pB.y) * ld;
        const float* r3 = tb + (size_t)__float_as_int(pB.w) * ld;
#pragma unroll
        for (int u = 0; u < GRP; ++u) {
            a0[u] = fmaf(pA.x, r0[sc[u]], a0[u]);
            a1[u] = fmaf(pA.z, r1[sc[u]], a1[u]);
            a2[u] = fmaf(pB.x, r2[sc[u]], a2[u]);
            a3[u] = fmaf(pB.z, r3[sc[u]], a3[u]);
        }
    }
    for (; q < cc.x; ++q) {
        float2 f = pb[q];
        const float* r0 = tb + (size_t)__float_as_int(f.y) * ld;
#pragma unroll
        for (int u = 0; u < GRP; ++u) a0[u] = fmaf(f.x, r0[sc[u]], a0[u]);
    }
    for (int v = 0; v < cc.y; ++v) {            // tiny-weight tail (spmm only)
        float2 f = pb[(NPAIR - 1) - v];
        const float* r0 = tb + (size_t)__float_as_int(f.y) * ld;
#pragma unroll
        for (int u = 0; u < GRP; ++u) a0[u] = fmaf(f.x, r0[sc[u]], a0[u]);
    }
    unsigned yv[GRP];
#pragma unroll
    for (int u = 0; u < GRP; ++u)
        yv[u] = __float_as_uint(
            fmaxf((a0[u] + a1[u]) + (a2[u] + a3[u]) + bi[u], 0.f));

    // scatter: for each out-neighbor r of j, p[r,c] = max(p[r,c], y[j,c]).
    // y>=0 and p zero-init -> uint atomicMax == float max (exact).
    const int rc = revc[gj];
    const int* rv = revi + (size_t)gj * NPAIR;
    for (int e = 0; e < rc; ++e) {
        const size_t rowoff = (size_t)(bbase + rv[e]) * ld;
#pragma unroll
        for (int u = 0; u < GRP; ++u)
            if (c[u] < N) atomicMax(p + rowoff + c[u], yv[u]);
    }
}

// -------- tail: t4 = p3 . gc4_w (coalesced) ; y4 ; fc1 ; fin ; sigmoid ------
__global__ __launch_bounds__(256)
void tail_k(const float* __restrict__ p3,   // ld 76, 75 valid cols
            const float2* __restrict__ pairs, const int2* __restrict__ cnts,
            const float* __restrict__ gc4_w, const float* __restrict__ gc4_b,
            const float* __restrict__ fc1_w, const float* __restrict__ fc1_b,
            const float* __restrict__ fin_w, const float* __restrict__ fin_b,
            float* __restrict__ out)
{
    const int b = blockIdx.x, tid = threadIdx.x;
    const int wave = tid >> 6, lane = tid & 63;
    __shared__ float t4S[NN], y4S[NN], rS[3];
    const float* pb3 = p3 + (size_t)b * NN * 76;

    const float gw0 = gc4_w[lane];                       // lane<=63<75 valid
    const float gw1 = (lane < 11) ? gc4_w[64 + lane] : 0.f;
    const int c2 = 64 + min(lane, 10);                   // safe 2nd col (<76)
    for (int i = wave; i < NN; i += 4) {
        const float* row = pb3 + (size_t)i * 76;
        float v = row[lane] * gw0 + row[c2] * gw1;       // coalesced reads
#pragma unroll
        for (int off = 32; off; off >>= 1) v += __shfl_xor(v, off, 64);
        if (lane == 0) t4S[i] = v;
    }
    __syncthreads();
    if (tid < NN) {
        const float2* pb = pairs + ((size_t)b * NN + tid) * NPAIR;
        int2 c = cnts[b * NN + tid];
        float s = gc4_b[0];
        for (int q = 0; q < c.x; ++q) {
            float2 f = pb[q];
            s = fmaf(f.x, t4S[__float_as_int(f.y)], s);
        }
        for (int q = 0; q < c.y; ++q) {
            float2 f = pb[(NPAIR - 1) - q];
            s = fmaf(f.x, t4S[__float_as_int(f.y)], s);
        }
        y4S[tid] = fmaxf(s, 0.f);
    }
    __syncthreads();
    if (tid < 3) {
        float s = fc1_b[tid];
        for (int j = 0; j < 132; ++j)
            s = fmaf(y4S[1 + j], fc1_w[j * 3 + tid], s);
        rS[tid] = s;
    }
    __syncthreads();
    if (tid == 0) {
        float z = fin_b[0] + y4S[0] * fin_w[0] + rS[0] * fin_w[1]
                + rS[1] * fin_w[2] + rS[2] * fin_w[3];
        out[b] = 1.f / (1.f + expf(-z));
    }
}

extern "C" void kernel_launch(void* const* d_in, const int* in_sizes, int n_in,
                              void* d_out, int out_size, void* d_ws, size_t ws_size,
                              hipStream_t stream)
{
    const float* x     = (const float*)d_in[0];
    const float* adj   = (const float*)d_in[1];
    const float* emb_w = (const float*)d_in[2];
    const float* emb_b = (const float*)d_in[3];
    const float* gc1_w = (const float*)d_in[4];
    const float* gc1_b = (const float*)d_in[5];
    const float* gc2_w = (const float*)d_in[6];
    const float* gc2_b = (const float*)d_in[7];
    const float* gc3_w = (const float*)d_in[8];
    const float* gc3_b = (const float*)d_in[9];
    const float* gc4_w = (const float*)d_in[10];
    const float* gc4_b = (const float*)d_in[11];
    const float* fc1_w = (const float*)d_in[12];
    const float* fc1_b = (const float*)d_in[13];
    const float* fin_w = (const float*)d_in[14];
    const float* fin_b = (const float*)d_in[15];
    float* out = (float*)d_out;

    // ws: pairs 4.36MB | cnts 68KB | revi 2.18MB | revc 34KB | bA|bB|bC 8.72MB
    const long MR = 64L * NN;                    // 8512
    float2* pairs = (float2*)d_ws;
    int2*   cnts  = (int2*)(pairs + MR * NPAIR);
    int*    revi  = (int*)(cnts + MR);
    int*    revc  = revi + MR * NPAIR;
    float*  bA    = (float*)(revc + MR);
    float*  bB    = bA + MR * 256;
    float*  bC    = bB + MR * 256;

    // K1: emb GEMM (399) -> bC (h0, ld 152) + fwd prep (2128) + rev prep (2128)
    prep_emb_k<<<399 + 2128 + 2128, 256, 0, stream>>>(
        x, emb_w, emb_b, adj, pairs, cnts, revi, revc, bC);
    // K2: t1 = h0 @ gc1_w -> bA ld 256 ; zero bB (p1: 8512*256 floats)
    gemm_zero_k<1, 1><<<532 + 256, 256, 0, stream>>>(
        bC, 152, 150, gc1_w, 256, bA, 256, 256, 4,
        532, (float4*)bB, (int)(MR * 256 / 4));
    // K3: spmm+pool 1 -> p1 = bB
    spmmpool_k<4><<<2128, 256, 0, stream>>>(
        bA, 256, 256, gc1_b, pairs, cnts, revi, revc, (unsigned*)bB);
    // K4: t2 = p1 @ gc2_w -> bC ld 128 ; zero bA (p2: 8512*128 floats)
    gemm_zero_k<1, 1><<<266 + 128, 256, 0, stream>>>(
        bB, 256, 256, gc2_w, 128, bC, 128, 128, 2,
        266, (float4*)bA, (int)(MR * 128 / 4));
    // K5: spmm+pool 2 -> p2 = bA
    spmmpool_k<2><<<2128, 256, 0, stream>>>(
        bC, 128, 128, gc2_b, pairs, cnts, revi, revc, (unsigned*)bA);
    // K6: t3 = p2 @ gc3_w -> bB ld 76 ; zero bC (p3: 8512*76 floats)
    gemm_zero_k<1, 0><<<266 + 128, 256, 0, stream>>>(
        bA, 128, 128, gc3_w, 75, bB, 76, 76, 2,
        266, (float4*)bC, (int)(MR * 76 / 4));
    // K7: spmm+pool 3 -> p3 = bC (N=75, col group 2 masked at the atomic)
    spmmpool_k<2><<<2128, 256, 0, stream>>>(
        bB, 76, 75, gc3_b, pairs, cnts, revi, revc, (unsigned*)bC);
    // K8: tail (t4 coalesced dot + y4 + fc1 + fin)
    tail_k<<<64, 256, 0, stream>>>(bC, pairs, cnts, gc4_w, gc4_b,
                                   fc1_w, fc1_b, fin_w, fin_b, out);
}

// Round 14
// 303.856 us; speedup vs baseline: 1.0820x; 1.0820x over previous
//
#include <hip/hip_runtime.h>
#include <math.h>

// ---------------------------------------------------------------------------
// B=64 graphs, NN=133 nodes. 8 plain launches (dependency-chain floor):
//  K1 blk<2128: embgemm1 (one wave/row: t1[r]=relu(x[r]@emb_w+b)@gc1_w)
//     blk>=2128: fwd ballot prep (one wave/row)
//  K2 spmm1  y1=relu(A@t1+b1)        (GRP=4, 1 wave/row, R12-validated)
//  K3 poolgemm2 (wave/row): p1[r]=max_j y1[j] (float4 gathers) -> LDS ->
//     t2[r]=p1[r]@gc2_w  (p1 never materialized)
//  K4 spmm2  y2 (GRP=2)
//  K5 poolgemm3 (wave/row): t3[r]=pool(y2)[r]@gc3_w
//  K6 spmm3  y3 (GRP=2, N=75)
//  K7 t4_k: t4[r]=pool3(y3)[r].gc4_w (R12-validated)
//  K8 tail: y4 sparse + fc1 + fin -> sigmoid (R12-validated)
// Row-local fusions only: every merged stage depends on exactly its own row
// (R7/R11/R13 lessons: cross-row gathers in low-occupancy kernels and
// scatter atomics both lose; 8512 independent waves is the winning shape).
// Fwd lists: front=a>1e-5 (spmm+pool), back=0<a<=1e-5 (spmm only).
// ---------------------------------------------------------------------------

#define NN 133
#define NPAIR 64

// -------- K1: embgemm1 (blocks<2128) + fwd ballot prep (blocks>=2128) -------
__global__ __launch_bounds__(256)
void embgemm1_prep_k(const float* __restrict__ x,
                     const float* __restrict__ emb_w,  // 75 x 150
                     const float* __restrict__ emb_b,
                     const float* __restrict__ gc1_w,  // 150 x 256
                     const float* __restrict__ adj,
                     float2* __restrict__ pairs, int2* __restrict__ cnts,
                     float* __restrict__ t1)           // 8512 x 256
{
    __shared__ float xS[4][80];
    __shared__ float hS[4][152];
    const int tid = threadIdx.x;
    const int wave = tid >> 6, lane = tid & 63;
    if (blockIdx.x < 2128) {
        const int r = blockIdx.x * 4 + wave;           // 0..8511
        const float* xr = x + (size_t)r * 75;
        xS[wave][lane] = xr[lane];                     // cols 0..63
        if (lane < 11) xS[wave][64 + lane] = xr[64 + lane];
        // h = relu(x@emb_w + emb_b): cols lane, 64+lane, 128+lane(<22)
        const int c2 = 128 + min(lane, 21);
        float s0 = emb_b[lane], s1 = emb_b[64 + lane], s2 = emb_b[c2];
#pragma unroll 5
        for (int k = 0; k < 75; ++k) {
            const float xk = xS[wave][k];
            const float* wr = emb_w + (size_t)k * 150;
            s0 = fmaf(xk, wr[lane], s0);
            s1 = fmaf(xk, wr[64 + lane], s1);
            s2 = fmaf(xk, wr[c2], s2);
        }
        hS[wave][lane] = fmaxf(s0, 0.f);
        hS[wave][64 + lane] = fmaxf(s1, 0.f);
        if (lane < 22) hS[wave][128 + lane] = fmaxf(s2, 0.f);
        // t1[r, 4*lane..+3] = h @ gc1_w  (coalesced float4 W reads)
        const float4* W4 = reinterpret_cast<const float4*>(gc1_w);
        float4 acc = make_float4(0.f, 0.f, 0.f, 0.f);
#pragma unroll 5
        for (int k = 0; k < 150; ++k) {
            const float hk = hS[wave][k];
            const float4 w = W4[(size_t)k * 64 + lane];
            acc.x = fmaf(hk, w.x, acc.x);
            acc.y = fmaf(hk, w.y, acc.y);
            acc.z = fmaf(hk, w.z, acc.z);
            acc.w = fmaf(hk, w.w, acc.w);
        }
        *reinterpret_cast<float4*>(t1 + (size_t)r * 256 + 4 * lane) = acc;
    } else {
        // fwd lists: one wave per adjacency row r (ballot compaction)
        const int r = (blockIdx.x - 2128) * 4 + wave;  // 0..8511
        const float* ar = adj + (size_t)r * NN;
        float2* pb = pairs + (size_t)r * NPAIR;
        const unsigned long long lt = (1ull << lane) - 1ull;
        int base0 = 0, base1 = 0;
#pragma unroll
        for (int s = 0; s < 3; ++s) {
            const int j = lane + 64 * s;
            const float a = (j < NN) ? ar[j] : 0.f;
            const bool f = a > 1e-5f;
            const bool g = (a > 0.f) && !f;
            const unsigned long long mf = __ballot(f);
            const unsigned long long mg = __ballot(g);
            if (f) pb[base0 + __popcll(mf & lt)] =
                       make_float2(a, __int_as_float(j));
            if (g) pb[(NPAIR - 1) - (base1 + __popcll(mg & lt))] =
                       make_float2(a, __int_as_float(j));
            base0 += __popcll(mf);
            base1 += __popcll(mg);
        }
        if (lane == 0) cnts[r] = make_int2(base0, base1);
    }
}

// -------- spmm: one wave per row, GRP*64 cols; 4 gather chains (R12) --------
template<int GRP>
__global__ __launch_bounds__(256)
void spmm_k(const float* __restrict__ t, int ld, int N,
            const float* __restrict__ bias,
            const float2* __restrict__ pairs, const int2* __restrict__ cnts,
            float* __restrict__ y)
{
    const int wave = threadIdx.x >> 6, lane = threadIdx.x & 63;
    const int r = blockIdx.x * 4 + wave;        // 0..8511
    const int b = r / NN;
    int  c[GRP], sc[GRP];
#pragma unroll
    for (int u = 0; u < GRP; ++u) {
        c[u] = u * 64 + lane;
        sc[u] = min(c[u], N - 1);               // clamp for safe loads
    }
    const float2* pb = pairs + (size_t)r * NPAIR;
    const float4* pq = reinterpret_cast<const float4*>(pb);
    const int2 cc = cnts[r];
    const float* tb = t + (size_t)b * NN * ld;

    float a0[GRP], a1[GRP], a2[GRP], a3[GRP];
#pragma unroll
    for (int u = 0; u < GRP; ++u) { a0[u] = a1[u] = a2[u] = a3[u] = 0.f; }
    int q = 0;
    for (; q + 4 <= cc.x; q += 4) {             // 4 independent gather chains
        float4 pA = pq[q >> 1], pB = pq[(q >> 1) + 1];
        const float* r0 = tb + (size_t)__float_as_int(pA.y) * ld;
        const float* r1 = tb + (size_t)__float_as_int(pA.w) * ld;
        const float* r2 = tb + (size_t)__float_as_int(pB.y) * ld;
        const float* r3 = tb + (size_t)__float_as_int(pB.w) * ld;
#pragma unroll
        for (int u = 0; u < GRP; ++u) {
            a0[u] = fmaf(pA.x, r0[sc[u]], a0[u]);
            a1[u] = fmaf(pA.z, r1[sc[u]], a1[u]);
            a2[u] = fmaf(pB.x, r2[sc[u]], a2[u]);
            a3[u] = fmaf(pB.z, r3[sc[u]], a3[u]);
        }
    }
    for (; q < cc.x; ++q) {
        float2 f = pb[q];
        const float* r0 = tb + (size_t)__float_as_int(f.y) * ld;
#pragma unroll
        for (int u = 0; u < GRP; ++u) a0[u] = fmaf(f.x, r0[sc[u]], a0[u]);
    }
    for (int v = 0; v < cc.y; ++v) {            // tiny-weight tail (spmm only)
        float2 f = pb[(NPAIR - 1) - v];
        const float* r0 = tb + (size_t)__float_as_int(f.y) * ld;
#pragma unroll
        for (int u = 0; u < GRP; ++u) a0[u] = fmaf(f.x, r0[sc[u]], a0[u]);
    }
#pragma unroll
    for (int u = 0; u < GRP; ++u)
        if (c[u] < N)
            y[(size_t)r * ld + c[u]] =
                fmaxf((a0[u] + a1[u]) + (a2[u] + a3[u]) + bias[c[u]], 0.f);
}

// -------- poolgemm2: t2[r] = (max_j y1[j]) @ gc2_w, one wave per row --------
__global__ __launch_bounds__(256)
void poolgemm2_k(const float* __restrict__ y1,     // ld 256
                 const float2* __restrict__ pairs, const int2* __restrict__ cnts,
                 const float* __restrict__ W,      // 256 x 128
                 float* __restrict__ t2)           // ld 128
{
    __shared__ float pS[4][260];
    const int tid = threadIdx.x;
    const int wave = tid >> 6, lane = tid & 63;
    const int r = blockIdx.x * 4 + wave;        // 0..8511
    const int b = r / NN;
    const float* yb = y1 + (size_t)b * NN * 256;
    const float2* pb = pairs + (size_t)r * NPAIR;
    const float4* pq = reinterpret_cast<const float4*>(pb);
    const int cx = cnts[r].x;

    // pool: p[r, 4*lane..+3] = max over front nbrs (float4 coalesced gathers)
    float4 m0 = make_float4(0.f, 0.f, 0.f, 0.f), m1 = m0;
    int q = 0;
    for (; q + 2 <= cx; q += 2) {
        float4 p2 = pq[q >> 1];
        const float4 v0 = *reinterpret_cast<const float4*>(
            yb + (size_t)__float_as_int(p2.y) * 256 + 4 * lane);
        const float4 v1 = *reinterpret_cast<const float4*>(
            yb + (size_t)__float_as_int(p2.w) * 256 + 4 * lane);
        m0.x = fmaxf(m0.x, v0.x); m0.y = fmaxf(m0.y, v0.y);
        m0.z = fmaxf(m0.z, v0.z); m0.w = fmaxf(m0.w, v0.w);
        m1.x = fmaxf(m1.x, v1.x); m1.y = fmaxf(m1.y, v1.y);
        m1.z = fmaxf(m1.z, v1.z); m1.w = fmaxf(m1.w, v1.w);
    }
    if (q < cx) {
        const float4 v0 = *reinterpret_cast<const float4*>(
            yb + (size_t)__float_as_int(pb[q].y) * 256 + 4 * lane);
        m0.x = fmaxf(m0.x, v0.x); m0.y = fmaxf(m0.y, v0.y);
        m0.z = fmaxf(m0.z, v0.z); m0.w = fmaxf(m0.w, v0.w);
    }
    m0.x = fmaxf(m0.x, m1.x); m0.y = fmaxf(m0.y, m1.y);
    m0.z = fmaxf(m0.z, m1.z); m0.w = fmaxf(m0.w, m1.w);
    *reinterpret_cast<float4*>(&pS[wave][4 * lane]) = m0;   // wave-local

    // gemm: t2[r, 2*lane..+1] = p @ W (LDS broadcast + coalesced float2 W)
    const float2* W2 = reinterpret_cast<const float2*>(W);
    float ax = 0.f, ay = 0.f;
#pragma unroll 8
    for (int k = 0; k < 256; ++k) {
        const float pk = pS[wave][k];
        const float2 w = W2[(size_t)k * 64 + lane];
        ax = fmaf(pk, w.x, ax);
        ay = fmaf(pk, w.y, ay);
    }
    *reinterpret_cast<float2*>(t2 + (size_t)r * 128 + 2 * lane) =
        make_float2(ax, ay);
}

// -------- poolgemm3: t3[r] = (max_j y2[j]) @ gc3_w, one wave per row --------
__global__ __launch_bounds__(256)
void poolgemm3_k(const float* __restrict__ y2,     // ld 128
                 const float2* __restrict__ pairs, const int2* __restrict__ cnts,
                 const float* __restrict__ W,      // 128 x 75
                 float* __restrict__ t3)           // ld 76
{
    __shared__ float pS[4][132];
    const int tid = threadIdx.x;
    const int wave = tid >> 6, lane = tid & 63;
    const int r = blockIdx.x * 4 + wave;
    const int b = r / NN;
    const float* yb = y2 + (size_t)b * NN * 128;
    const float2* pb = pairs + (size_t)r * NPAIR;
    const float4* pq = reinterpret_cast<const float4*>(pb);
    const int cx = cnts[r].x;

    float2 m0 = make_float2(0.f, 0.f), m1 = m0;
    int q = 0;
    for (; q + 2 <= cx; q += 2) {
        float4 p2 = pq[q >> 1];
        const float2 v0 = *reinterpret_cast<const float2*>(
            yb + (size_t)__float_as_int(p2.y) * 128 + 2 * lane);
        const float2 v1 = *reinterpret_cast<const float2*>(
            yb + (size_t)__float_as_int(p2.w) * 128 + 2 * lane);
        m0.x = fmaxf(m0.x, v0.x); m0.y = fmaxf(m0.y, v0.y);
        m1.x = fmaxf(m1.x, v1.x); m1.y = fmaxf(m1.y, v1.y);
    }
    if (q < cx) {
        const float2 v0 = *reinterpret_cast<const float2*>(
            yb + (size_t)__float_as_int(pb[q].y) * 128 + 2 * lane);
        m0.x = fmaxf(m0.x, v0.x); m0.y = fmaxf(m0.y, v0.y);
    }
    m0.x = fmaxf(m0.x, m1.x); m0.y = fmaxf(m0.y, m1.y);
    *reinterpret_cast<float2*>(&pS[wave][2 * lane]) = m0;   // wave-local

    // gemm: cols lane and 64+lane (lane<11); W rows are 75 floats
    const int c1 = 64 + min(lane, 10);
    float a0 = 0.f, a1 = 0.f;
#pragma unroll 8
    for (int k = 0; k < 128; ++k) {
        const float pk = pS[wave][k];
        const float* wr = W + (size_t)k * 75;
        a0 = fmaf(pk, wr[lane], a0);
        a1 = fmaf(pk, wr[c1], a1);
    }
    t3[(size_t)r * 76 + lane] = a0;
    if (lane < 11) t3[(size_t)r * 76 + 64 + lane] = a1;
}

// -------- t4: t4[r] = dot(pool3(y3)[r,0:75], gc4_w), one wave per row (R12) -
__global__ __launch_bounds__(256)
void t4_k(const float* __restrict__ y3,   // ld 76, 75 valid cols
          const float2* __restrict__ pairs, const int2* __restrict__ cnts,
          const float* __restrict__ gc4_w,
          float* __restrict__ t4)         // 8512
{
    const int wave = threadIdx.x >> 6, lane = threadIdx.x & 63;
    const int r = blockIdx.x * 4 + wave;        // 0..8511
    const int b = r / NN;
    const float* yb = y3 + (size_t)b * NN * 76;
    const float2* pb = pairs + (size_t)r * NPAIR;
    const float4* pq = reinterpret_cast<const float4*>(pb);
    const int cx = cnts[r].x;
    const float gw0 = gc4_w[lane];                       // lane<=63<75 valid
    const float gw1 = (lane < 11) ? gc4_w[64 + lane] : 0.f;
    const int c2 = 64 + min(lane, 10);                   // safe 2nd col

    float m0a = 0.f, m1a = 0.f, m0b = 0.f, m1b = 0.f;
    float m0c = 0.f, m1c = 0.f, m0d = 0.f, m1d = 0.f;
    int q = 0;
    for (; q + 4 <= cx; q += 4) {               // 4 independent gather chains
        float4 pA = pq[q >> 1], pB = pq[(q >> 1) + 1];
        const float* r0 = yb + (size_t)__float_as_int(pA.y) * 76;
        const float* r1 = yb + (size_t)__float_as_int(pA.w) * 76;
        const float* r2 = yb + (size_t)__float_as_int(pB.y) * 76;
        const float* r3 = yb + (size_t)__float_as_int(pB.w) * 76;
        m0a = fmaxf(m0a, r0[lane]); m1a = fmaxf(m1a, r0[c2]);
        m0b = fmaxf(m0b, r1[lane]); m1b = fmaxf(m1b, r1[c2]);
        m0c = fmaxf(m0c, r2[lane]); m1c = fmaxf(m1c, r2[c2]);
        m0d = fmaxf(m0d, r3[lane]); m1d = fmaxf(m1d, r3[c2]);
    }
    for (; q < cx; ++q) {
        const float* r0 = yb + (size_t)__float_as_int(pb[q].y) * 76;
        m0a = fmaxf(m0a, r0[lane]); m1a = fmaxf(m1a, r0[c2]);
    }
    float m0 = fmaxf(fmaxf(m0a, m0b), fmaxf(m0c, m0d));
    float m1 = fmaxf(fmaxf(m1a, m1b), fmaxf(m1c, m1d));
    float v = m0 * gw0 + m1 * gw1;
#pragma unroll
    for (int off = 32; off; off >>= 1) v += __shfl_xor(v, off, 64);
    if (lane == 0) t4[r] = v;
}

// -------- tail: y4 = relu(A@t4+b4); fc1; fin; sigmoid (64 blocks) (R12) -----
__global__ __launch_bounds__(256)
void tail_k(const float* __restrict__ t4g,  // 8512
            const float2* __restrict__ pairs, const int2* __restrict__ cnts,
            const float* __restrict__ gc4_b,
            const float* __restrict__ fc1_w, const float* __restrict__ fc1_b,
            const float* __restrict__ fin_w, const float* __restrict__ fin_b,
            float* __restrict__ out)
{
    const int b = blockIdx.x, tid = threadIdx.x;
    __shared__ float t4S[NN], y4S[NN], rS[3];
    if (tid < NN) t4S[tid] = t4g[b * NN + tid];
    __syncthreads();
    if (tid < NN) {
        const float2* pb = pairs + ((size_t)b * NN + tid) * NPAIR;
        int2 c = cnts[b * NN + tid];
        float s = gc4_b[0];
        for (int q = 0; q < c.x; ++q) {
            float2 f = pb[q];
            s = fmaf(f.x, t4S[__float_as_int(f.y)], s);
        }
        for (int q = 0; q < c.y; ++q) {
            float2 f = pb[(NPAIR - 1) - q];
            s = fmaf(f.x, t4S[__float_as_int(f.y)], s);
        }
        y4S[tid] = fmaxf(s, 0.f);
    }
    __syncthreads();
    if (tid < 3) {
        float s = fc1_b[tid];
        for (int j = 0; j < 132; ++j)
            s = fmaf(y4S[1 + j], fc1_w[j * 3 + tid], s);
        rS[tid] = s;
    }
    __syncthreads();
    if (tid == 0) {
        float z = fin_b[0] + y4S[0] * fin_w[0] + rS[0] * fin_w[1]
                + rS[1] * fin_w[2] + rS[2] * fin_w[3];
        out[b] = 1.f / (1.f + expf(-z));
    }
}

extern "C" void kernel_launch(void* const* d_in, const int* in_sizes, int n_in,
                              void* d_out, int out_size, void* d_ws, size_t ws_size,
                              hipStream_t stream)
{
    const float* x     = (const float*)d_in[0];
    const float* adj   = (const float*)d_in[1];
    const float* emb_w = (const float*)d_in[2];
    const float* emb_b = (const float*)d_in[3];
    const float* gc1_w = (const float*)d_in[4];
    const float* gc1_b = (const float*)d_in[5];
    const float* gc2_w = (const float*)d_in[6];
    const float* gc2_b = (const float*)d_in[7];
    const float* gc3_w = (const float*)d_in[8];
    const float* gc3_b = (const float*)d_in[9];
    const float* gc4_w = (const float*)d_in[10];
    const float* gc4_b = (const float*)d_in[11];
    const float* fc1_w = (const float*)d_in[12];
    const float* fc1_b = (const float*)d_in[13];
    const float* fin_w = (const float*)d_in[14];
    const float* fin_b = (const float*)d_in[15];
    float* out = (float*)d_out;

    // ws: pairs 4.36MB | cnts 68KB | bA 8.72MB | bB 8.72MB | bC 8.72MB | t4
    const long MR = 64L * NN;                    // 8512
    float2* pairs = (float2*)d_ws;
    int2*   cnts  = (int2*)(pairs + MR * NPAIR);
    float*  bA    = (float*)(cnts + MR);
    float*  bB    = bA + MR * 256;
    float*  bC    = bB + MR * 256;
    float*  t4    = bC + MR * 256;               // 8512 floats

    // K1: t1 = relu(x@emb_w+b)@gc1_w -> bA (ld 256) ; fwd ballot prep
    embgemm1_prep_k<<<2128 + 2128, 256, 0, stream>>>(
        x, emb_w, emb_b, gc1_w, adj, pairs, cnts, bA);
    // K2: y1 = relu(A@t1+b1) -> bB (ld 256)
    spmm_k<4><<<2128, 256, 0, stream>>>(bA, 256, 256, gc1_b, pairs, cnts, bB);
    // K3: t2 = pool(y1) @ gc2_w -> bC (ld 128)  [row-local fused pool+gemm]
    poolgemm2_k<<<2128, 256, 0, stream>>>(bB, pairs, cnts, gc2_w, bC);
    // K4: y2 = relu(A@t2+b2) -> bA (ld 128)
    spmm_k<2><<<2128, 256, 0, stream>>>(bC, 128, 128, gc2_b, pairs, cnts, bA);
    // K5: t3 = pool(y2) @ gc3_w -> bB (ld 76)
    poolgemm3_k<<<2128, 256, 0, stream>>>(bA, pairs, cnts, gc3_w, bB);
    // K6: y3 = relu(A@t3+b3) -> bC (ld 76, N=75)
    spmm_k<2><<<2128, 256, 0, stream>>>(bB, 76, 75, gc3_b, pairs, cnts, bC);
    // K7: t4[r] = pool3(y3)[r] . gc4_w
    t4_k<<<2128, 256, 0, stream>>>(bC, pairs, cnts, gc4_w, t4);
    // K8: tail
    tail_k<<<64, 256, 0, stream>>>(t4, pairs, cnts, gc4_b,
                                   fc1_w, fc1_b, fin_w, fin_b, out);
}

// Round 15
// 238.522 us; speedup vs baseline: 1.3784x; 1.2739x over previous
//
#include <hip/hip_runtime.h>
#include <math.h>

// ---------------------------------------------------------------------------
// B=64 graphs, NN=133 nodes. 9 plain launches (R12 base + big-block fusions):
//  K1 prep_emb : blk<399 emb GEMM tiles; blk>=399 fwd ballot prep (wave/row)
//  K2 gemm1 t1=h0@gc1_w (532 tiles, LDS-amortized W)
//  K3 spmm1 y1 (GRP=4, 1 wave/row)
//  K4 poolgemm2_big: 16 rows/block (1024 thr): pool(y1)->LDS pS, then
//     t2 = pS @ gc2_w with W k-tiles staged in LDS (shared by 16 rows)
//  K5 spmm2 y2 (GRP=2)
//  K6 poolgemm3_big: same, full gc3_w (128x76) staged once in LDS
//  K7 spmm3 y3 (GRP=2, N=75)
//  K8 t4_k: t4[r]=pool3(y3)[r].gc4_w (1 wave/row)
//  K9 tail: y4 sparse + fc1 + fin -> sigmoid (64 blocks)
// R14 lesson: per-wave GEMM streams W privately (1.1GB L2) — W must be
// LDS-shared across rows. R7/R11/R13 lessons: keep 8512-wave parallel shape,
// no cross-row gathers in low-occupancy kernels, no scatter atomics.
// Fwd lists: front=a>1e-5 (spmm+pool), back=0<a<=1e-5 (spmm only).
// ---------------------------------------------------------------------------

#define NN 133
#define NPAIR 64

// ---------------- GEMM core: one 64x64 tile, prefetch-pipelined -------------
template<int VECA, int VECB, int RELU, int BIAS>
__device__ __forceinline__ void gemm_tile_core(
    const float* __restrict__ A, int lda, int K,
    const float* __restrict__ W, int N,
    const float* __restrict__ bias,
    float* __restrict__ C, int ldc, int padN,
    int m0, int n0, float (*As)[68], float (*Bs)[68], int tid)
{
    const int la_m = tid >> 2, la_k = (tid & 3) * 4;   // A: 64 rows x 4 float4
    const int lb_k = tid >> 4, lb_n = (tid & 15) * 4;  // B: 16 k-rows x 16 f4
    const int tx = tid & 15, ty = tid >> 4;
    const int r = m0 + la_m;

    float pa[4], pb[4];
    if (VECA) {
        float4 v = *reinterpret_cast<const float4*>(A + (size_t)r * lda + la_k);
        pa[0] = v.x; pa[1] = v.y; pa[2] = v.z; pa[3] = v.w;
    } else {
#pragma unroll
        for (int j = 0; j < 4; ++j) {
            int gk = la_k + j;
            pa[j] = (gk < K) ? A[(size_t)r * lda + gk] : 0.f;
        }
    }
    if (VECB) {
        if (lb_k < K) {
            float4 v = *reinterpret_cast<const float4*>(
                W + (size_t)lb_k * N + n0 + lb_n);
            pb[0] = v.x; pb[1] = v.y; pb[2] = v.z; pb[3] = v.w;
        } else { pb[0] = pb[1] = pb[2] = pb[3] = 0.f; }
    } else {
#pragma unroll
        for (int j = 0; j < 4; ++j) {
            int gn = n0 + lb_n + j;
            pb[j] = (lb_k < K && gn < N) ? W[(size_t)lb_k * N + gn] : 0.f;
        }
    }

    float acc[4][4] = {};
    for (int k0 = 0; k0 < K; k0 += 16) {
        __syncthreads();
#pragma unroll
        for (int j = 0; j < 4; ++j) As[la_k + j][la_m] = pa[j];
        *reinterpret_cast<float4*>(&Bs[lb_k][lb_n]) =
            make_float4(pb[0], pb[1], pb[2], pb[3]);
        __syncthreads();
        const int kn = k0 + 16;
        if (kn < K) {   // prefetch next k-tile (overlaps FMA block)
            if (VECA) {
                float4 v = *reinterpret_cast<const float4*>(
                    A + (size_t)r * lda + kn + la_k);
                pa[0] = v.x; pa[1] = v.y; pa[2] = v.z; pa[3] = v.w;
            } else {
#pragma unroll
                for (int j = 0; j < 4; ++j) {
                    int gk = kn + la_k + j;
                    pa[j] = (gk < K) ? A[(size_t)r * lda + gk] : 0.f;
                }
            }
            int gk = kn + lb_k;
            if (VECB) {
                if (gk < K) {
                    float4 v = *reinterpret_cast<const float4*>(
                        W + (size_t)gk * N + n0 + lb_n);
                    pb[0] = v.x; pb[1] = v.y; pb[2] = v.z; pb[3] = v.w;
                } else { pb[0] = pb[1] = pb[2] = pb[3] = 0.f; }
            } else {
#pragma unroll
                for (int j = 0; j < 4; ++j) {
                    int gn = n0 + lb_n + j;
                    pb[j] = (gk < K && gn < N) ? W[(size_t)gk * N + gn] : 0.f;
                }
            }
        }
#pragma unroll
        for (int k = 0; k < 16; ++k) {
            float4 av = *reinterpret_cast<const float4*>(&As[k][ty * 4]);
            float4 bv = *reinterpret_cast<const float4*>(&Bs[k][tx * 4]);
            float a[4] = {av.x, av.y, av.z, av.w};
            float b[4] = {bv.x, bv.y, bv.z, bv.w};
#pragma unroll
            for (int i = 0; i < 4; ++i)
#pragma unroll
                for (int j = 0; j < 4; ++j)
                    acc[i][j] = fmaf(a[i], b[j], acc[i][j]);
        }
    }
#pragma unroll
    for (int i = 0; i < 4; ++i) {
        int gm = m0 + ty * 4 + i;
#pragma unroll
        for (int j = 0; j < 4; ++j) {
            int gn = n0 + tx * 4 + j;
            if (gn < padN) {
                float v = 0.f;
                if (gn < N) {
                    v = acc[i][j];
                    if (BIAS) v += bias[gn];
                    if (RELU) v = fmaxf(v, 0.f);
                }
                C[(size_t)gm * ldc + gn] = v;
            }
        }
    }
}

template<int VECA, int VECB>
__global__ __launch_bounds__(256)
void gemm_k(const float* __restrict__ A, int lda, int K,
            const float* __restrict__ W, int N,
            float* __restrict__ C, int ldc, int padN, int tiles_n)
{
    __shared__ float As[16][68];
    __shared__ float Bs[16][68];
    const int t = blockIdx.x;
    gemm_tile_core<VECA, VECB, 0, 0>(
        A, lda, K, W, N, nullptr, C, ldc, padN,
        (t / tiles_n) * 64, (t % tiles_n) * 64, As, Bs, threadIdx.x);
}

// -------- K1: emb GEMM tiles (blocks<399) + ballot prep (blocks>=399) -------
__global__ __launch_bounds__(256)
void prep_emb_k(const float* __restrict__ x,
                const float* __restrict__ emb_w, const float* __restrict__ emb_b,
                const float* __restrict__ adj,
                float2* __restrict__ pairs, int2* __restrict__ cnts,
                float* __restrict__ h0)
{
    __shared__ float As[16][68];
    __shared__ float Bs[16][68];
    const int tid = threadIdx.x;
    if (blockIdx.x < 399) {
        const int t = blockIdx.x;
        gemm_tile_core<0, 0, 1, 1>(
            x, 75, 75, emb_w, 150, emb_b, h0, 152, 152,
            (t / 3) * 64, (t % 3) * 64, As, Bs, tid);
    } else {
        const int wave = tid >> 6, lane = tid & 63;
        const int r = (blockIdx.x - 399) * 4 + wave;   // 0..8511
        const float* ar = adj + (size_t)r * NN;
        float2* pb = pairs + (size_t)r * NPAIR;
        const unsigned long long lt = (1ull << lane) - 1ull;
        int base0 = 0, base1 = 0;
#pragma unroll
        for (int s = 0; s < 3; ++s) {
            const int j = lane + 64 * s;
            const float a = (j < NN) ? ar[j] : 0.f;
            const bool f = a > 1e-5f;
            const bool g = (a > 0.f) && !f;
            const unsigned long long mf = __ballot(f);
            const unsigned long long mg = __ballot(g);
            if (f) pb[base0 + __popcll(mf & lt)] =
                       make_float2(a, __int_as_float(j));
            if (g) pb[(NPAIR - 1) - (base1 + __popcll(mg & lt))] =
                       make_float2(a, __int_as_float(j));
            base0 += __popcll(mf);
            base1 += __popcll(mg);
        }
        if (lane == 0) cnts[r] = make_int2(base0, base1);
    }
}

// -------- spmm: one wave per row, GRP*64 cols; 4 gather chains (R12) --------
template<int GRP>
__global__ __launch_bounds__(256)
void spmm_k(const float* __restrict__ t, int ld, int N,
            const float* __restrict__ bias,
            const float2* __restrict__ pairs, const int2* __restrict__ cnts,
            float* __restrict__ y)
{
    const int wave = threadIdx.x >> 6, lane = threadIdx.x & 63;
    const int r = blockIdx.x * 4 + wave;        // 0..8511
    const int b = r / NN;
    int  c[GRP], sc[GRP];
#pragma unroll
    for (int u = 0; u < GRP; ++u) {
        c[u] = u * 64 + lane;
        sc[u] = min(c[u], N - 1);               // clamp for safe loads
    }
    const float2* pb = pairs + (size_t)r * NPAIR;
    const float4* pq = reinterpret_cast<const float4*>(pb);
    const int2 cc = cnts[r];
    const float* tb = t + (size_t)b * NN * ld;

    float a0[GRP], a1[GRP], a2[GRP], a3[GRP];
#pragma unroll
    for (int u = 0; u < GRP; ++u) { a0[u] = a1[u] = a2[u] = a3[u] = 0.f; }
    int q = 0;
    for (; q + 4 <= cc.x; q += 4) {             // 4 independent gather chains
        float4 pA = pq[q >> 1], pB = pq[(q >> 1) + 1];
        const float* r0 = tb + (size_t)__float_as_int(pA.y) * ld;
        const float* r1 = tb + (size_t)__float_as_int(pA.w) * ld;
        const float* r2 = tb + (size_t)__float_as_int(pB.y) * ld;
        const float* r3 = tb + (size_t)__float_as_int(pB.w) * ld;
#pragma unroll
        for (int u = 0; u < GRP; ++u) {
            a0[u] = fmaf(pA.x, r0[sc[u]], a0[u]);
            a1[u] = fmaf(pA.z, r1[sc[u]], a1[u]);
            a2[u] = fmaf(pB.x, r2[sc[u]], a2[u]);
            a3[u] = fmaf(pB.z, r3[sc[u]], a3[u]);
        }
    }
    for (; q < cc.x; ++q) {
        float2 f = pb[q];
        const float* r0 = tb + (size_t)__float_as_int(f.y) * ld;
#pragma unroll
        for (int u = 0; u < GRP; ++u) a0[u] = fmaf(f.x, r0[sc[u]], a0[u]);
    }
    for (int v = 0; v < cc.y; ++v) {            // tiny-weight tail (spmm only)
        float2 f = pb[(NPAIR - 1) - v];
        const float* r0 = tb + (size_t)__float_as_int(f.y) * ld;
#pragma unroll
        for (int u = 0; u < GRP; ++u) a0[u] = fmaf(f.x, r0[sc[u]], a0[u]);
    }
#pragma unroll
    for (int u = 0; u < GRP; ++u)
        if (c[u] < N)
            y[(size_t)r * ld + c[u]] =
                fmaxf((a0[u] + a1[u]) + (a2[u] + a3[u]) + bias[c[u]], 0.f);
}

// -------- poolgemm2_big: 16 rows/block; t2 = pool(y1) @ gc2_w ---------------
// Pool into LDS pS[16][256]; W k-tiles (64x128 = 32KB) staged in LDS shared
// by all 16 rows -> W traffic /16 vs per-wave streaming (R14 fix).
__global__ __launch_bounds__(1024)
void poolgemm2_big(const float* __restrict__ y1,     // ld 256
                   const float2* __restrict__ pairs,
                   const int2* __restrict__ cnts,
                   const float* __restrict__ W,      // 256 x 128
                   float* __restrict__ t2)           // ld 128
{
    __shared__ float pS[16][256];
    __shared__ float Ws[64 * 128];
    const int tid = threadIdx.x;
    const int wave = tid >> 6, lane = tid & 63;
    const int r = blockIdx.x * 16 + wave;       // 532*16 = 8512 exact
    const int b = r / NN;

    // ---- pool: pS[wave][4*lane..+3] = max over front nbrs of y1[j] ----
    const float* yb = y1 + (size_t)b * NN * 256;
    const float2* pb = pairs + (size_t)r * NPAIR;
    const float4* pq = reinterpret_cast<const float4*>(pb);
    const int cx = cnts[r].x;
    float4 m0 = make_float4(0.f, 0.f, 0.f, 0.f), m1 = m0;
    int q = 0;
    for (; q + 2 <= cx; q += 2) {
        float4 p2 = pq[q >> 1];
        const float4 v0 = *reinterpret_cast<const float4*>(
            yb + (size_t)__float_as_int(p2.y) * 256 + 4 * lane);
        const float4 v1 = *reinterpret_cast<const float4*>(
            yb + (size_t)__float_as_int(p2.w) * 256 + 4 * lane);
        m0.x = fmaxf(m0.x, v0.x); m0.y = fmaxf(m0.y, v0.y);
        m0.z = fmaxf(m0.z, v0.z); m0.w = fmaxf(m0.w, v0.w);
        m1.x = fmaxf(m1.x, v1.x); m1.y = fmaxf(m1.y, v1.y);
        m1.z = fmaxf(m1.z, v1.z); m1.w = fmaxf(m1.w, v1.w);
    }
    if (q < cx) {
        const float4 v0 = *reinterpret_cast<const float4*>(
            yb + (size_t)__float_as_int(pb[q].y) * 256 + 4 * lane);
        m0.x = fmaxf(m0.x, v0.x); m0.y = fmaxf(m0.y, v0.y);
        m0.z = fmaxf(m0.z, v0.z); m0.w = fmaxf(m0.w, v0.w);
    }
    m0.x = fmaxf(m0.x, m1.x); m0.y = fmaxf(m0.y, m1.y);
    m0.z = fmaxf(m0.z, m1.z); m0.w = fmaxf(m0.w, m1.w);
    *reinterpret_cast<float4*>(&pS[wave][4 * lane]) = m0;

    // ---- gemm: t2[r, 2*lane..+1], k-tiled W in LDS ----
    float ax = 0.f, ay = 0.f;
    for (int k0 = 0; k0 < 256; k0 += 64) {
        __syncthreads();                        // Ws readers done / pS ready
        const float4* Wg = reinterpret_cast<const float4*>(W + (size_t)k0 * 128);
        float4* Ws4 = reinterpret_cast<float4*>(Ws);
        Ws4[tid] = Wg[tid];                     // 2048 float4 total
        Ws4[tid + 1024] = Wg[tid + 1024];
        __syncthreads();
#pragma unroll 8
        for (int k = 0; k < 64; ++k) {
            const float pk = pS[wave][k0 + k];  // wave-uniform broadcast
            const float2 w = *reinterpret_cast<const float2*>(
                &Ws[k * 128 + 2 * lane]);
            ax = fmaf(pk, w.x, ax);
            ay = fmaf(pk, w.y, ay);
        }
    }
    *reinterpret_cast<float2*>(t2 + (size_t)r * 128 + 2 * lane) =
        make_float2(ax, ay);
}

// -------- poolgemm3_big: 16 rows/block; t3 = pool(y2) @ gc3_w ---------------
// Full gc3_w (128x75, padded to 76) staged once in LDS (38.9KB).
__global__ __launch_bounds__(1024)
void poolgemm3_big(const float* __restrict__ y2,     // ld 128
                   const float2* __restrict__ pairs,
                   const int2* __restrict__ cnts,
                   const float* __restrict__ W,      // 128 x 75
                   float* __restrict__ t3)           // ld 76
{
    __shared__ float pS[16][128];
    __shared__ float Wf[128 * 76];
    const int tid = threadIdx.x;
    const int wave = tid >> 6, lane = tid & 63;
    const int r = blockIdx.x * 16 + wave;
    const int b = r / NN;

    // stage full W (pad row stride to 76)
    for (int idx = tid; idx < 128 * 75; idx += 1024) {
        const int k = idx / 75, cc = idx - k * 75;
        Wf[k * 76 + cc] = W[idx];
    }

    // ---- pool: pS[wave][2*lane..+1] = max over front nbrs of y2[j] ----
    const float* yb = y2 + (size_t)b * NN * 128;
    const float2* pb = pairs + (size_t)r * NPAIR;
    const float4* pq = reinterpret_cast<const float4*>(pb);
    const int cx = cnts[r].x;
    float2 m0 = make_float2(0.f, 0.f), m1 = m0;
    int q = 0;
    for (; q + 2 <= cx; q += 2) {
        float4 p2 = pq[q >> 1];
        const float2 v0 = *reinterpret_cast<const float2*>(
            yb + (size_t)__float_as_int(p2.y) * 128 + 2 * lane);
        const float2 v1 = *reinterpret_cast<const float2*>(
            yb + (size_t)__float_as_int(p2.w) * 128 + 2 * lane);
        m0.x = fmaxf(m0.x, v0.x); m0.y = fmaxf(m0.y, v0.y);
        m1.x = fmaxf(m1.x, v1.x); m1.y = fmaxf(m1.y, v1.y);
    }
    if (q < cx) {
        const float2 v0 = *reinterpret_cast<const float2*>(
            yb + (size_t)__float_as_int(pb[q].y) * 128 + 2 * lane);
        m0.x = fmaxf(m0.x, v0.x); m0.y = fmaxf(m0.y, v0.y);
    }
    m0.x = fmaxf(m0.x, m1.x); m0.y = fmaxf(m0.y, m1.y);
    *reinterpret_cast<float2*>(&pS[wave][2 * lane]) = m0;
    __syncthreads();                            // Wf + all pS visible

    // ---- gemm: cols lane and 64+lane (lane<11) ----
    const int c1 = 64 + min(lane, 10);
    float a0 = 0.f, a1 = 0.f;
#pragma unroll 8
    for (int k = 0; k < 128; ++k) {
        const float pk = pS[wave][k];           // wave-uniform broadcast
        a0 = fmaf(pk, Wf[k * 76 + lane], a0);
        a1 = fmaf(pk, Wf[k * 76 + c1], a1);
    }
    t3[(size_t)r * 76 + lane] = a0;
    if (lane < 11) t3[(size_t)r * 76 + 64 + lane] = a1;
}

// -------- t4: t4[r] = dot(pool3(y3)[r,0:75], gc4_w), one wave per row (R12) -
__global__ __launch_bounds__(256)
void t4_k(const float* __restrict__ y3,   // ld 76, 75 valid cols
          const float2* __restrict__ pairs, const int2* __restrict__ cnts,
          const float* __restrict__ gc4_w,
          float* __restrict__ t4)         // 8512
{
    const int wave = threadIdx.x >> 6, lane = threadIdx.x & 63;
    const int r = blockIdx.x * 4 + wave;        // 0..8511
    const int b = r / NN;
    const float* yb = y3 + (size_t)b * NN * 76;
    const float2* pb = pairs + (size_t)r * NPAIR;
    const float4* pq = reinterpret_cast<const float4*>(pb);
    const int cx = cnts[r].x;
    const float gw0 = gc4_w[lane];                       // lane<=63<75 valid
    const float gw1 = (lane < 11) ? gc4_w[64 + lane] : 0.f;
    const int c2 = 64 + min(lane, 10);                   // safe 2nd col

    float m0a = 0.f, m1a = 0.f, m0b = 0.f, m1b = 0.f;
    float m0c = 0.f, m1c = 0.f, m0d = 0.f, m1d = 0.f;
    int q = 0;
    for (; q + 4 <= cx; q += 4) {               // 4 independent gather chains
        float4 pA = pq[q >> 1], pB = pq[(q >> 1) + 1];
        const float* r0 = yb + (size_t)__float_as_int(pA.y) * 76;
        const float* r1 = yb + (size_t)__float_as_int(pA.w) * 76;
        const float* r2 = yb + (size_t)__float_as_int(pB.y) * 76;
        const float* r3 = yb + (size_t)__float_as_int(pB.w) * 76;
        m0a = fmaxf(m0a, r0[lane]); m1a = fmaxf(m1a, r0[c2]);
        m0b = fmaxf(m0b, r1[lane]); m1b = fmaxf(m1b, r1[c2]);
        m0c = fmaxf(m0c, r2[lane]); m1c = fmaxf(m1c, r2[c2]);
        m0d = fmaxf(m0d, r3[lane]); m1d = fmaxf(m1d, r3[c2]);
    }
    for (; q < cx; ++q) {
        const float* r0 = yb + (size_t)__float_as_int(pb[q].y) * 76;
        m0a = fmaxf(m0a, r0[lane]); m1a = fmaxf(m1a, r0[c2]);
    }
    float m0 = fmaxf(fmaxf(m0a, m0b), fmaxf(m0c, m0d));
    float m1 = fmaxf(fmaxf(m1a, m1b), fmaxf(m1c, m1d));
    float v = m0 * gw0 + m1 * gw1;
#pragma unroll
    for (int off = 32; off; off >>= 1) v += __shfl_xor(v, off, 64);
    if (lane == 0) t4[r] = v;
}

// -------- tail: y4 = relu(A@t4+b4); fc1; fin; sigmoid (64 blocks) (R12) -----
__global__ __launch_bounds__(256)
void tail_k(const float* __restrict__ t4g,  // 8512
            const float2* __restrict__ pairs, const int2* __restrict__ cnts,
            const float* __restrict__ gc4_b,
            const float* __restrict__ fc1_w, const float* __restrict__ fc1_b,
            const float* __restrict__ fin_w, const float* __restrict__ fin_b,
            float* __restrict__ out)
{
    const int b = blockIdx.x, tid = threadIdx.x;
    __shared__ float t4S[NN], y4S[NN], rS[3];
    if (tid < NN) t4S[tid] = t4g[b * NN + tid];
    __syncthreads();
    if (tid < NN) {
        const float2* pb = pairs + ((size_t)b * NN + tid) * NPAIR;
        int2 c = cnts[b * NN + tid];
        float s = gc4_b[0];
        for (int q = 0; q < c.x; ++q) {
            float2 f = pb[q];
            s = fmaf(f.x, t4S[__float_as_int(f.y)], s);
        }
        for (int q = 0; q < c.y; ++q) {
            float2 f = pb[(NPAIR - 1) - q];
            s = fmaf(f.x, t4S[__float_as_int(f.y)], s);
        }
        y4S[tid] = fmaxf(s, 0.f);
    }
    __syncthreads();
    if (tid < 3) {
        float s = fc1_b[tid];
        for (int j = 0; j < 132; ++j)
            s = fmaf(y4S[1 + j], fc1_w[j * 3 + tid], s);
        rS[tid] = s;
    }
    __syncthreads();
    if (tid == 0) {
        float z = fin_b[0] + y4S[0] * fin_w[0] + rS[0] * fin_w[1]
                + rS[1] * fin_w[2] + rS[2] * fin_w[3];
        out[b] = 1.f / (1.f + expf(-z));
    }
}

extern "C" void kernel_launch(void* const* d_in, const int* in_sizes, int n_in,
                              void* d_out, int out_size, void* d_ws, size_t ws_size,
                              hipStream_t stream)
{
    const float* x     = (const float*)d_in[0];
    const float* adj   = (const float*)d_in[1];
    const float* emb_w = (const float*)d_in[2];
    const float* emb_b = (const float*)d_in[3];
    const float* gc1_w = (const float*)d_in[4];
    const float* gc1_b = (const float*)d_in[5];
    const float* gc2_w = (const float*)d_in[6];
    const float* gc2_b = (const float*)d_in[7];
    const float* gc3_w = (const float*)d_in[8];
    const float* gc3_b = (const float*)d_in[9];
    const float* gc4_w = (const float*)d_in[10];
    const float* gc4_b = (const float*)d_in[11];
    const float* fc1_w = (const float*)d_in[12];
    const float* fc1_b = (const float*)d_in[13];
    const float* fin_w = (const float*)d_in[14];
    const float* fin_b = (const float*)d_in[15];
    float* out = (float*)d_out;

    // ws: pairs 4.36MB | cnts 68KB | bA 8.72MB | bB 8.72MB | bC 8.72MB | t4
    const long MR = 64L * NN;                    // 8512
    float2* pairs = (float2*)d_ws;
    int2*   cnts  = (int2*)(pairs + MR * NPAIR);
    float*  bA    = (float*)(cnts + MR);
    float*  bB    = bA + MR * 256;
    float*  bC    = bB + MR * 256;
    float*  t4    = bC + MR * 256;               // 8512 floats

    // K1: emb GEMM (399 tiles) -> bC (h0, ld 152) + ballot prep (2128 blocks)
    prep_emb_k<<<399 + 2128, 256, 0, stream>>>(x, emb_w, emb_b, adj,
                                               pairs, cnts, bC);
    // K2: t1 = h0 @ gc1_w -> bA ld 256
    gemm_k<1, 1><<<532, 256, 0, stream>>>(bC, 152, 150, gc1_w, 256,
                                          bA, 256, 256, 4);
    // K3: y1 = relu(A@t1+b1) -> bB (ld 256)
    spmm_k<4><<<2128, 256, 0, stream>>>(bA, 256, 256, gc1_b, pairs, cnts, bB);
    // K4: t2 = pool(y1) @ gc2_w -> bC (ld 128)  [big-block fused]
    poolgemm2_big<<<532, 1024, 0, stream>>>(bB, pairs, cnts, gc2_w, bC);
    // K5: y2 = relu(A@t2+b2) -> bA (ld 128)
    spmm_k<2><<<2128, 256, 0, stream>>>(bC, 128, 128, gc2_b, pairs, cnts, bA);
    // K6: t3 = pool(y2) @ gc3_w -> bB (ld 76)  [big-block fused]
    poolgemm3_big<<<532, 1024, 0, stream>>>(bA, pairs, cnts, gc3_w, bB);
    // K7: y3 = relu(A@t3+b3) -> bC (ld 76, N=75)
    spmm_k<2><<<2128, 256, 0, stream>>>(bB, 76, 75, gc3_b, pairs, cnts, bC);
    // K8: t4[r] = pool3(y3)[r] . gc4_w
    t4_k<<<2128, 256, 0, stream>>>(bC, pairs, cnts, gc4_w, t4);
    // K9: tail
    tail_k<<<64, 256, 0, stream>>>(t4, pairs, cnts, gc4_b,
                                   fc1_w, fc1_b, fin_w, fin_b, out);
}

// Round 16
// 221.346 us; speedup vs baseline: 1.4854x; 1.0776x over previous
//
#include <hip/hip_runtime.h>
#include <math.h>

// ---------------------------------------------------------------------------
// B=64 graphs, NN=133 nodes. 11 plain launches (R12 structure = validated
// best, 223.6us; + 8 gather chains in GRP=2 sparse kernels):
//  K1 prep_emb : blk<399 emb GEMM tiles; blk>=399 fwd ballot prep (wave/row)
//  K2 gemm1 t1=h0@gc1_w (532 tiles)       K3 spmm1 (GRP=4, 4 chains)
//  K4 pool1 (GRP=4, 4 chains)             K5 gemm2 (266)
//  K6 spmm2 (GRP=2, 8 chains)             K7 pool2 (GRP=2, 8 chains)
//  K8 gemm3 (266)                         K9 spmm3 (GRP=2, 8 chains)
//  K10 t4_k (4 chains)                    K11 tail (64 blocks)
// Session lessons baked in: separate pool/gemm kernels (fusion closed by
// R7/R11/R13/R14/R15), no scatter atomics (R13), no SW grid barrier (R8),
// 8512-wave shape for all sparse work, ballot prep, VGPR < 64 everywhere.
// Fwd lists: front=a>1e-5 (spmm+pool), back=0<a<=1e-5 (spmm only).
// ---------------------------------------------------------------------------

#define NN 133
#define NPAIR 64

// ---------------- GEMM core: one 64x64 tile, prefetch-pipelined -------------
template<int VECA, int VECB, int RELU, int BIAS>
__device__ __forceinline__ void gemm_tile_core(
    const float* __restrict__ A, int lda, int K,
    const float* __restrict__ W, int N,
    const float* __restrict__ bias,
    float* __restrict__ C, int ldc, int padN,
    int m0, int n0, float (*As)[68], float (*Bs)[68], int tid)
{
    const int la_m = tid >> 2, la_k = (tid & 3) * 4;   // A: 64 rows x 4 float4
    const int lb_k = tid >> 4, lb_n = (tid & 15) * 4;  // B: 16 k-rows x 16 f4
    const int tx = tid & 15, ty = tid >> 4;
    const int r = m0 + la_m;

    float pa[4], pb[4];
    if (VECA) {
        float4 v = *reinterpret_cast<const float4*>(A + (size_t)r * lda + la_k);
        pa[0] = v.x; pa[1] = v.y; pa[2] = v.z; pa[3] = v.w;
    } else {
#pragma unroll
        for (int j = 0; j < 4; ++j) {
            int gk = la_k + j;
            pa[j] = (gk < K) ? A[(size_t)r * lda + gk] : 0.f;
        }
    }
    if (VECB) {
        if (lb_k < K) {
            float4 v = *reinterpret_cast<const float4*>(
                W + (size_t)lb_k * N + n0 + lb_n);
            pb[0] = v.x; pb[1] = v.y; pb[2] = v.z; pb[3] = v.w;
        } else { pb[0] = pb[1] = pb[2] = pb[3] = 0.f; }
    } else {
#pragma unroll
        for (int j = 0; j < 4; ++j) {
            int gn = n0 + lb_n + j;
            pb[j] = (lb_k < K && gn < N) ? W[(size_t)lb_k * N + gn] : 0.f;
        }
    }

    float acc[4][4] = {};
    for (int k0 = 0; k0 < K; k0 += 16) {
        __syncthreads();
#pragma unroll
        for (int j = 0; j < 4; ++j) As[la_k + j][la_m] = pa[j];
        *reinterpret_cast<float4*>(&Bs[lb_k][lb_n]) =
            make_float4(pb[0], pb[1], pb[2], pb[3]);
        __syncthreads();
        const int kn = k0 + 16;
        if (kn < K) {   // prefetch next k-tile (overlaps FMA block)
            if (VECA) {
                float4 v = *reinterpret_cast<const float4*>(
                    A + (size_t)r * lda + kn + la_k);
                pa[0] = v.x; pa[1] = v.y; pa[2] = v.z; pa[3] = v.w;
            } else {
#pragma unroll
                for (int j = 0; j < 4; ++j) {
                    int gk = kn + la_k + j;
                    pa[j] = (gk < K) ? A[(size_t)r * lda + gk] : 0.f;
                }
            }
            int gk = kn + lb_k;
            if (VECB) {
                if (gk < K) {
                    float4 v = *reinterpret_cast<const float4*>(
                        W + (size_t)gk * N + n0 + lb_n);
                    pb[0] = v.x; pb[1] = v.y; pb[2] = v.z; pb[3] = v.w;
                } else { pb[0] = pb[1] = pb[2] = pb[3] = 0.f; }
            } else {
#pragma unroll
                for (int j = 0; j < 4; ++j) {
                    int gn = n0 + lb_n + j;
                    pb[j] = (gk < K && gn < N) ? W[(size_t)gk * N + gn] : 0.f;
                }
            }
        }
#pragma unroll
        for (int k = 0; k < 16; ++k) {
            float4 av = *reinterpret_cast<const float4*>(&As[k][ty * 4]);
            float4 bv = *reinterpret_cast<const float4*>(&Bs[k][tx * 4]);
            float a[4] = {av.x, av.y, av.z, av.w};
            float b[4] = {bv.x, bv.y, bv.z, bv.w};
#pragma unroll
            for (int i = 0; i < 4; ++i)
#pragma unroll
                for (int j = 0; j < 4; ++j)
                    acc[i][j] = fmaf(a[i], b[j], acc[i][j]);
        }
    }
#pragma unroll
    for (int i = 0; i < 4; ++i) {
        int gm = m0 + ty * 4 + i;
#pragma unroll
        for (int j = 0; j < 4; ++j) {
            int gn = n0 + tx * 4 + j;
            if (gn < padN) {
                float v = 0.f;
                if (gn < N) {
                    v = acc[i][j];
                    if (BIAS) v += bias[gn];
                    if (RELU) v = fmaxf(v, 0.f);
                }
                C[(size_t)gm * ldc + gn] = v;
            }
        }
    }
}

template<int VECA, int VECB>
__global__ __launch_bounds__(256)
void gemm_k(const float* __restrict__ A, int lda, int K,
            const float* __restrict__ W, int N,
            float* __restrict__ C, int ldc, int padN, int tiles_n)
{
    __shared__ float As[16][68];
    __shared__ float Bs[16][68];
    const int t = blockIdx.x;
    gemm_tile_core<VECA, VECB, 0, 0>(
        A, lda, K, W, N, nullptr, C, ldc, padN,
        (t / tiles_n) * 64, (t % tiles_n) * 64, As, Bs, threadIdx.x);
}

// -------- K1: emb GEMM tiles (blocks<399) + ballot prep (blocks>=399) -------
__global__ __launch_bounds__(256)
void prep_emb_k(const float* __restrict__ x,
                const float* __restrict__ emb_w, const float* __restrict__ emb_b,
                const float* __restrict__ adj,
                float2* __restrict__ pairs, int2* __restrict__ cnts,
                float* __restrict__ h0)
{
    __shared__ float As[16][68];
    __shared__ float Bs[16][68];
    const int tid = threadIdx.x;
    if (blockIdx.x < 399) {
        const int t = blockIdx.x;
        gemm_tile_core<0, 0, 1, 1>(
            x, 75, 75, emb_w, 150, emb_b, h0, 152, 152,
            (t / 3) * 64, (t % 3) * 64, As, Bs, tid);
    } else {
        const int wave = tid >> 6, lane = tid & 63;
        const int r = (blockIdx.x - 399) * 4 + wave;   // 0..8511
        const float* ar = adj + (size_t)r * NN;
        float2* pb = pairs + (size_t)r * NPAIR;
        const unsigned long long lt = (1ull << lane) - 1ull;
        int base0 = 0, base1 = 0;
#pragma unroll
        for (int s = 0; s < 3; ++s) {
            const int j = lane + 64 * s;
            const float a = (j < NN) ? ar[j] : 0.f;
            const bool f = a > 1e-5f;
            const bool g = (a > 0.f) && !f;
            const unsigned long long mf = __ballot(f);
            const unsigned long long mg = __ballot(g);
            if (f) pb[base0 + __popcll(mf & lt)] =
                       make_float2(a, __int_as_float(j));
            if (g) pb[(NPAIR - 1) - (base1 + __popcll(mg & lt))] =
                       make_float2(a, __int_as_float(j));
            base0 += __popcll(mf);
            base1 += __popcll(mg);
        }
        if (lane == 0) cnts[r] = make_int2(base0, base1);
    }
}

// -------- spmm: one wave per row, GRP*64 cols; CH gather chains -------------
template<int GRP, int CH>
__global__ __launch_bounds__(256)
void spmm_k(const float* __restrict__ t, int ld, int N,
            const float* __restrict__ bias,
            const float2* __restrict__ pairs, const int2* __restrict__ cnts,
            float* __restrict__ y)
{
    const int wave = threadIdx.x >> 6, lane = threadIdx.x & 63;
    const int r = blockIdx.x * 4 + wave;        // 0..8511
    const int b = r / NN;
    int  c[GRP], sc[GRP];
#pragma unroll
    for (int u = 0; u < GRP; ++u) {
        c[u] = u * 64 + lane;
        sc[u] = min(c[u], N - 1);               // clamp for safe loads
    }
    const float2* pb = pairs + (size_t)r * NPAIR;
    const float4* pq = reinterpret_cast<const float4*>(pb);
    const int2 cc = cnts[r];
    const float* tb = t + (size_t)b * NN * ld;

    float acc[CH][GRP];
#pragma unroll
    for (int h = 0; h < CH; ++h)
#pragma unroll
        for (int u = 0; u < GRP; ++u) acc[h][u] = 0.f;

    int q = 0;
    for (; q + CH <= cc.x; q += CH) {           // CH independent gather chains
        const float* rp[CH];
        float wv[CH];
#pragma unroll
        for (int h = 0; h < CH; h += 2) {
            float4 pp = pq[(q + h) >> 1];
            wv[h] = pp.x;     rp[h]     = tb + (size_t)__float_as_int(pp.y) * ld;
            wv[h + 1] = pp.z; rp[h + 1] = tb + (size_t)__float_as_int(pp.w) * ld;
        }
#pragma unroll
        for (int h = 0; h < CH; ++h)
#pragma unroll
            for (int u = 0; u < GRP; ++u)
                acc[h][u] = fmaf(wv[h], rp[h][sc[u]], acc[h][u]);
    }
    for (; q + 2 <= cc.x; q += 2) {
        float4 pp = pq[q >> 1];
        const float* r0 = tb + (size_t)__float_as_int(pp.y) * ld;
        const float* r1 = tb + (size_t)__float_as_int(pp.w) * ld;
#pragma unroll
        for (int u = 0; u < GRP; ++u) {
            acc[0][u] = fmaf(pp.x, r0[sc[u]], acc[0][u]);
            acc[1][u] = fmaf(pp.z, r1[sc[u]], acc[1][u]);
        }
    }
    if (q < cc.x) {
        float2 f = pb[q];
        const float* r0 = tb + (size_t)__float_as_int(f.y) * ld;
#pragma unroll
        for (int u = 0; u < GRP; ++u) acc[0][u] = fmaf(f.x, r0[sc[u]], acc[0][u]);
    }
    for (int v = 0; v < cc.y; ++v) {            // tiny-weight tail (spmm only)
        float2 f = pb[(NPAIR - 1) - v];
        const float* r0 = tb + (size_t)__float_as_int(f.y) * ld;
#pragma unroll
        for (int u = 0; u < GRP; ++u) acc[0][u] = fmaf(f.x, r0[sc[u]], acc[0][u]);
    }
#pragma unroll
    for (int u = 0; u < GRP; ++u) {
        if (c[u] < N) {
            float s = 0.f;
#pragma unroll
            for (int h = 0; h < CH; ++h) s += acc[h][u];
            y[(size_t)r * ld + c[u]] = fmaxf(s + bias[c[u]], 0.f);
        }
    }
}

// -------- pool: p[r,col] = max over front nbrs j of y[j,col] (y>=0) ---------
template<int GRP, int CH>
__global__ __launch_bounds__(256)
void pool_k(const float* __restrict__ y, int ld, int N,
            const float2* __restrict__ pairs, const int2* __restrict__ cnts,
            float* __restrict__ p)
{
    const int wave = threadIdx.x >> 6, lane = threadIdx.x & 63;
    const int r = blockIdx.x * 4 + wave;
    const int b = r / NN;
    int  c[GRP], sc[GRP];
#pragma unroll
    for (int u = 0; u < GRP; ++u) {
        c[u] = u * 64 + lane;
        sc[u] = min(c[u], N - 1);
    }
    const float2* pb = pairs + (size_t)r * NPAIR;
    const float4* pq = reinterpret_cast<const float4*>(pb);
    const int cx = cnts[r].x;
    const float* yb = y + (size_t)b * NN * ld;

    float m[CH][GRP];
#pragma unroll
    for (int h = 0; h < CH; ++h)
#pragma unroll
        for (int u = 0; u < GRP; ++u) m[h][u] = 0.f;

    int q = 0;
    for (; q + CH <= cx; q += CH) {
        const float* rp[CH];
#pragma unroll
        for (int h = 0; h < CH; h += 2) {
            float4 pp = pq[(q + h) >> 1];
            rp[h]     = yb + (size_t)__float_as_int(pp.y) * ld;
            rp[h + 1] = yb + (size_t)__float_as_int(pp.w) * ld;
        }
#pragma unroll
        for (int h = 0; h < CH; ++h)
#pragma unroll
            for (int u = 0; u < GRP; ++u)
                m[h][u] = fmaxf(m[h][u], rp[h][sc[u]]);
    }
    for (; q + 2 <= cx; q += 2) {
        float4 pp = pq[q >> 1];
        const float* r0 = yb + (size_t)__float_as_int(pp.y) * ld;
        const float* r1 = yb + (size_t)__float_as_int(pp.w) * ld;
#pragma unroll
        for (int u = 0; u < GRP; ++u) {
            m[0][u] = fmaxf(m[0][u], r0[sc[u]]);
            m[1][u] = fmaxf(m[1][u], r1[sc[u]]);
        }
    }
    if (q < cx) {
        const float* r0 = yb + (size_t)__float_as_int(pb[q].y) * ld;
#pragma unroll
        for (int u = 0; u < GRP; ++u) m[0][u] = fmaxf(m[0][u], r0[sc[u]]);
    }
#pragma unroll
    for (int u = 0; u < GRP; ++u) {
        if (c[u] < N) {
            float s = 0.f;
#pragma unroll
            for (int h = 0; h < CH; ++h) s = fmaxf(s, m[h][u]);
            p[(size_t)r * ld + c[u]] = s;
        }
    }
}

// -------- t4: t4[r] = dot(pool3(y3)[r,0:75], gc4_w), one wave per row -------
__global__ __launch_bounds__(256)
void t4_k(const float* __restrict__ y3,   // ld 76, 75 valid cols
          const float2* __restrict__ pairs, const int2* __restrict__ cnts,
          const float* __restrict__ gc4_w,
          float* __restrict__ t4)         // 8512
{
    const int wave = threadIdx.x >> 6, lane = threadIdx.x & 63;
    const int r = blockIdx.x * 4 + wave;        // 0..8511
    const int b = r / NN;
    const float* yb = y3 + (size_t)b * NN * 76;
    const float2* pb = pairs + (size_t)r * NPAIR;
    const float4* pq = reinterpret_cast<const float4*>(pb);
    const int cx = cnts[r].x;
    const float gw0 = gc4_w[lane];                       // lane<=63<75 valid
    const float gw1 = (lane < 11) ? gc4_w[64 + lane] : 0.f;
    const int c2 = 64 + min(lane, 10);                   // safe 2nd col

    float m0a = 0.f, m1a = 0.f, m0b = 0.f, m1b = 0.f;
    float m0c = 0.f, m1c = 0.f, m0d = 0.f, m1d = 0.f;
    int q = 0;
    for (; q + 4 <= cx; q += 4) {               // 4 independent gather chains
        float4 pA = pq[q >> 1], pB = pq[(q >> 1) + 1];
        const float* r0 = yb + (size_t)__float_as_int(pA.y) * 76;
        const float* r1 = yb + (size_t)__float_as_int(pA.w) * 76;
        const float* r2 = yb + (size_t)__float_as_int(pB.y) * 76;
        const float* r3 = yb + (size_t)__float_as_int(pB.w) * 76;
        m0a = fmaxf(m0a, r0[lane]); m1a = fmaxf(m1a, r0[c2]);
        m0b = fmaxf(m0b, r1[lane]); m1b = fmaxf(m1b, r1[c2]);
        m0c = fmaxf(m0c, r2[lane]); m1c = fmaxf(m1c, r2[c2]);
        m0d = fmaxf(m0d, r3[lane]); m1d = fmaxf(m1d, r3[c2]);
    }
    for (; q < cx; ++q) {
        const float* r0 = yb + (size_t)__float_as_int(pb[q].y) * 76;
        m0a = fmaxf(m0a, r0[lane]); m1a = fmaxf(m1a, r0[c2]);
    }
    float m0 = fmaxf(fmaxf(m0a, m0b), fmaxf(m0c, m0d));
    float m1 = fmaxf(fmaxf(m1a, m1b), fmaxf(m1c, m1d));
    float v = m0 * gw0 + m1 * gw1;
#pragma unroll
    for (int off = 32; off; off >>= 1) v += __shfl_xor(v, off, 64);
    if (lane == 0) t4[r] = v;
}

// -------- tail: y4 = relu(A@t4+b4); fc1; fin; sigmoid (64 blocks, tiny) -----
__global__ __launch_bounds__(256)
void tail_k(const float* __restrict__ t4g,  // 8512
            const float2* __restrict__ pairs, const int2* __restrict__ cnts,
            const float* __restrict__ gc4_b,
            const float* __restrict__ fc1_w, const float* __restrict__ fc1_b,
            const float* __restrict__ fin_w, const float* __restrict__ fin_b,
            float* __restrict__ out)
{
    const int b = blockIdx.x, tid = threadIdx.x;
    __shared__ float t4S[NN], y4S[NN], rS[3];
    if (tid < NN) t4S[tid] = t4g[b * NN + tid];
    __syncthreads();
    if (tid < NN) {
        const float2* pb = pairs + ((size_t)b * NN + tid) * NPAIR;
        int2 c = cnts[b * NN + tid];
        float s = gc4_b[0];
        for (int q = 0; q < c.x; ++q) {
            float2 f = pb[q];
            s = fmaf(f.x, t4S[__float_as_int(f.y)], s);
        }
        for (int q = 0; q < c.y; ++q) {
            float2 f = pb[(NPAIR - 1) - q];
            s = fmaf(f.x, t4S[__float_as_int(f.y)], s);
        }
        y4S[tid] = fmaxf(s, 0.f);
    }
    __syncthreads();
    if (tid < 3) {
        float s = fc1_b[tid];
        for (int j = 0; j < 132; ++j)
            s = fmaf(y4S[1 + j], fc1_w[j * 3 + tid], s);
        rS[tid] = s;
    }
    __syncthreads();
    if (tid == 0) {
        float z = fin_b[0] + y4S[0] * fin_w[0] + rS[0] * fin_w[1]
                + rS[1] * fin_w[2] + rS[2] * fin_w[3];
        out[b] = 1.f / (1.f + expf(-z));
    }
}

extern "C" void kernel_launch(void* const* d_in, const int* in_sizes, int n_in,
                              void* d_out, int out_size, void* d_ws, size_t ws_size,
                              hipStream_t stream)
{
    const float* x     = (const float*)d_in[0];
    const float* adj   = (const float*)d_in[1];
    const float* emb_w = (const float*)d_in[2];
    const float* emb_b = (const float*)d_in[3];
    const float* gc1_w = (const float*)d_in[4];
    const float* gc1_b = (const float*)d_in[5];
    const float* gc2_w = (const float*)d_in[6];
    const float* gc2_b = (const float*)d_in[7];
    const float* gc3_w = (const float*)d_in[8];
    const float* gc3_b = (const float*)d_in[9];
    const float* gc4_w = (const float*)d_in[10];
    const float* gc4_b = (const float*)d_in[11];
    const float* fc1_w = (const float*)d_in[12];
    const float* fc1_b = (const float*)d_in[13];
    const float* fin_w = (const float*)d_in[14];
    const float* fin_b = (const float*)d_in[15];
    float* out = (float*)d_out;

    // ws: pairs 4.36MB | cnts 68KB | bA 8.72MB | bB 8.72MB | bC 8.72MB | t4
    const long MR = 64L * NN;                    // 8512
    float2* pairs = (float2*)d_ws;
    int2*   cnts  = (int2*)(pairs + MR * NPAIR);
    float*  bA    = (float*)(cnts + MR);
    float*  bB    = bA + MR * 256;
    float*  bC    = bB + MR * 256;
    float*  t4    = bC + MR * 256;               // 8512 floats

    // K1: emb GEMM (399 tiles) -> bC (h0, ld 152) + ballot prep (2128 blocks)
    prep_emb_k<<<399 + 2128, 256, 0, stream>>>(x, emb_w, emb_b, adj,
                                               pairs, cnts, bC);
    // K2: t1 = h0 @ gc1_w -> bA ld 256
    gemm_k<1, 1><<<532, 256, 0, stream>>>(bC, 152, 150, gc1_w, 256,
                                          bA, 256, 256, 4);
    // K3: y1 -> bB (one wave per row, 256 cols, 4 chains)
    spmm_k<4, 4><<<2128, 256, 0, stream>>>(bA, 256, 256, gc1_b,
                                           pairs, cnts, bB);
    // K4: p1 -> bC (4 chains)
    pool_k<4, 4><<<2128, 256, 0, stream>>>(bB, 256, 256, pairs, cnts, bC);
    // K5: t2 = p1 @ gc2_w -> bA ld 128
    gemm_k<1, 1><<<266, 256, 0, stream>>>(bC, 256, 256, gc2_w, 128,
                                          bA, 128, 128, 2);
    // K6: y2 -> bB (8 chains)
    spmm_k<2, 8><<<2128, 256, 0, stream>>>(bA, 128, 128, gc2_b,
                                           pairs, cnts, bB);
    // K7: p2 -> bC (8 chains)
    pool_k<2, 8><<<2128, 256, 0, stream>>>(bB, 128, 128, pairs, cnts, bC);
    // K8: t3 = p2 @ gc3_w -> bA ld 76 (padN=76 zero-fills col 75)
    gemm_k<1, 0><<<266, 256, 0, stream>>>(bC, 128, 128, gc3_w, 75,
                                          bA, 76, 76, 2);
    // K9: y3 -> bB (N=75, 8 chains)
    spmm_k<2, 8><<<2128, 256, 0, stream>>>(bA, 76, 75, gc3_b,
                                           pairs, cnts, bB);
    // K10: t4[r] = pool3(y3)[r] . gc4_w
    t4_k<<<2128, 256, 0, stream>>>(bB, pairs, cnts, gc4_w, t4);
    // K11: tail
    tail_k<<<64, 256, 0, stream>>>(t4, pairs, cnts, gc4_b,
                                   fc1_w, fc1_b, fin_w, fin_b, out);
}